// Round 9
// baseline (27.927 us; speedup 1.0000x reference)
//
#include <hip/hip_runtime.h>
#include <math.h>

#define BB 2048   // batch B
#define NN 512    // classes N
#define DD 256    // dim D

typedef __attribute__((ext_vector_type(8))) short s16x8;   // 8 bf16
typedef __attribute__((ext_vector_type(4))) float f32x4;

#define MFMA_BF16 __builtin_amdgcn_mfma_f32_16x16x32_bf16

__device__ __forceinline__ ushort f2bf(float f) {          // RNE f32->bf16
    union { float f; unsigned u; } c; c.f = f;
    return (ushort)((c.u + 0x7fffu + ((c.u >> 16) & 1u)) >> 16);
}
__device__ __forceinline__ float bf2f(ushort h) {
    union { unsigned u; float f; } c; c.u = ((unsigned)h) << 16;
    return c.f;
}

// scale 4 floats, split each into bf16 hi + bf16 lo (RNE both), pack pairs
__device__ __forceinline__ void split4(f32x4 v, float s, uint2* hi, uint2* lo) {
    float a = v.x * s, b = v.y * s, c = v.z * s, d = v.w * s;
    ushort ha = f2bf(a), hb = f2bf(b), hc = f2bf(c), hd = f2bf(d);
    ushort la = f2bf(a - bf2f(ha)), lb = f2bf(b - bf2f(hb));
    ushort lc = f2bf(c - bf2f(hc)), ld = f2bf(d - bf2f(hd));
    hi->x = (unsigned)ha | ((unsigned)hb << 16);
    hi->y = (unsigned)hc | ((unsigned)hd << 16);
    lo->x = (unsigned)la | ((unsigned)lb << 16);
    lo->y = (unsigned)lc | ((unsigned)ld << 16);
}

// ONE kernel, 256 blocks x 512 threads, NO cross-block communication.
// Block (b0 = (bid&31)*64, n0 = (bid>>5)*64) transforms its own 64 X rows
// and 64 P/A rows directly into LDS (duplicated across blocks - cheap VALU),
// then runs the dual compensated MFMA GEMM + fused asinh epilogue.
// LDS (dynamic, ushort elems):
//   Xh[64][256] @0, Xl @16384            (full K, 64 KiB)
//   Ph[64][128] @32768, Pl @40960,
//   Ah[64][128] @49152, Al @57344        (HALF K, 64 KiB; half1 overwrites)
//   float scalars @65536: y2s[64], p2sl[64], pasl[64], ansl[64], ksl[64]
__global__ __launch_bounds__(512, 1) void hmlr_fused(
    const float* __restrict__ x, const float* __restrict__ a_vals,
    const float* __restrict__ p_vals, float* __restrict__ out)
{
    extern __shared__ ushort T[];
    ushort* Xh  = T;
    ushort* Xl  = T + 16384;
    ushort* Phh = T + 32768;
    ushort* Pll = T + 40960;
    ushort* Ahh = T + 49152;
    ushort* All = T + 57344;
    float* y2s  = (float*)(T + 65536);
    float* p2sl = y2s + 64;
    float* pasl = y2s + 128;
    float* ansl = y2s + 192;
    float* ksl  = y2s + 256;

    const int t    = threadIdx.x;
    const int lane = t & 63;
    const int w    = t >> 6;               // wave 0..7
    const int bid  = blockIdx.x;
    const int b0   = (bid & 31) * 64;
    const int n0   = (bid >> 5) * 64;
    const int e0   = lane * 4;             // full-K elem base (X)
    const int c0   = (lane & 31) * 4;      // half-K elem base (P/A)

    // -------- phase 1a: transform this block's 64 X rows into LDS --------
    #pragma unroll
    for (int i = 0; i < 8; ++i) {
        int r = w * 8 + i;                 // block-local row
        f32x4 v = *(const f32x4*)&x[(size_t)(b0 + r) * DD + e0];
        float ss = v.x * v.x + v.y * v.y + v.z * v.z + v.w * v.w;
        #pragma unroll
        for (int m = 32; m; m >>= 1) ss += __shfl_xor(ss, m, 64);
        float norm0 = sqrtf(ss);
        float fac = fminf(1.0f, 1.0f / (norm0 + 1e-5f));    // CLIP_R = 1
        float u = fmaxf(norm0 * fac, 1e-5f);
        float th = tanhf(u);                                 // sqrt_c = 1
        float en = fmaxf(th, 1e-5f);
        float wgt = (en > 0.999f) ? (0.999f / en) : 1.0f;    // project
        float s = fac * (th / u) * wgt;                      // x -> xb scale
        if (lane == 0) { float fn = th * wgt; y2s[r] = fn * fn; }
        uint2 hi, lo;
        split4(v, s, &hi, &lo);
        int es = e0 ^ ((r & 7) << 3);                        // swizzle
        *(uint2*)&Xh[r * 256 + es] = hi;
        *(uint2*)&Xl[r * 256 + es] = lo;
    }

    // -------- phase 1b: transform this block's 64 P/A rows --------
    // lanes < 32 hold K-half 0 -> write now; lanes >= 32 keep packs in regs.
    uint2 ph1[8], pl1[8], ah1[8], al1[8];
    #pragma unroll
    for (int i = 0; i < 8; ++i) {
        int rn = w * 8 + i;                // block-local n row
        f32x4 pv = *(const f32x4*)&p_vals[(size_t)(n0 + rn) * DD + e0];
        f32x4 av = *(const f32x4*)&a_vals[(size_t)(n0 + rn) * DD + e0];
        float sp = pv.x * pv.x + pv.y * pv.y + pv.z * pv.z + pv.w * pv.w;
        float sa = av.x * av.x + av.y * av.y + av.z * av.z + av.w * av.w;
        float sx = pv.x * av.x + pv.y * av.y + pv.z * av.z + pv.w * av.w;
        #pragma unroll
        for (int m = 32; m; m >>= 1) {
            sp += __shfl_xor(sp, m, 64);
            sa += __shfl_xor(sa, m, 64);
            sx += __shfl_xor(sx, m, 64);
        }
        float u = fmaxf(sqrtf(sp), 1e-5f);
        float th = tanhf(u);
        float spp = th / u;                                  // p -> p_poincare
        float p2 = th * th;
        float conf = 1.0f - p2;                              // conformal
        if (lane == 0) {
            p2sl[rn] = p2;
            pasl[rn] = spp * conf * sx;                      // P . A
            float an = sqrtf(sa) * conf;                     // ||a_poincare||
            ansl[rn] = an;
            ksl[rn] = (2.0f / conf) * an;                    // lam * a_norm
        }
        uint2 hp, lp, ha, la;
        split4(pv, spp, &hp, &lp);
        split4(av, conf, &ha, &la);
        int cs = c0 ^ ((rn & 7) << 3);
        if (lane < 32) {                                     // K-half 0
            *(uint2*)&Phh[rn * 128 + cs] = hp;
            *(uint2*)&Pll[rn * 128 + cs] = lp;
            *(uint2*)&Ahh[rn * 128 + cs] = ha;
            *(uint2*)&All[rn * 128 + cs] = la;
        } else {                                             // hold K-half 1
            ph1[i] = hp; pl1[i] = lp; ah1[i] = ha; al1[i] = la;
        }
    }
    __syncthreads();

    // -------- GEMM setup --------
    const int wr   = w >> 2;               // b half (32 rows)
    const int wc   = w & 3;                // n strip (16 cols)
    const int gb8  = (lane >> 4) * 8;      // 16B group (elems)
    const int ram  = wr * 32 + (lane & 15);
    const int rbn  = wc * 16 + (lane & 15);
    const int swzA = (ram & 7) << 3;       // same for ram+16
    const int swzB = (rbn & 7) << 3;
    f32x4 axy0 = {0.f,0.f,0.f,0.f}, axy1 = {0.f,0.f,0.f,0.f};
    f32x4 axa0 = {0.f,0.f,0.f,0.f}, axa1 = {0.f,0.f,0.f,0.f};

    const ushort* r0h = Xh + ram * 256;
    const ushort* r1h = Xh + (ram + 16) * 256;
    const ushort* r0l = Xl + ram * 256;
    const ushort* r1l = Xl + (ram + 16) * 256;
    const ushort* bph = Phh + rbn * 128;
    const ushort* bpl = Pll + rbn * 128;
    const ushort* bah = Ahh + rbn * 128;
    const ushort* bal = All + rbn * 128;

    // -------- K-half 0: q = 0..3 --------
    #pragma unroll
    for (int q = 0; q < 4; ++q) {
        int kb  = (q * 32 + gb8) ^ swzA;       // X elem offset (full-K tile)
        int kbB = (q * 32 + gb8) ^ swzB;       // P/A elem offset (half tile)
        s16x8 xh0 = *(const s16x8*)(r0h + kb);
        s16x8 xh1 = *(const s16x8*)(r1h + kb);
        s16x8 xl0 = *(const s16x8*)(r0l + kb);
        s16x8 xl1 = *(const s16x8*)(r1l + kb);
        s16x8 ph  = *(const s16x8*)(bph + kbB);
        s16x8 pl  = *(const s16x8*)(bpl + kbB);
        s16x8 ah  = *(const s16x8*)(bah + kbB);
        s16x8 al  = *(const s16x8*)(bal + kbB);
        axy0 = MFMA_BF16(xh0, ph, axy0, 0, 0, 0);
        axy0 = MFMA_BF16(xh0, pl, axy0, 0, 0, 0);
        axy0 = MFMA_BF16(xl0, ph, axy0, 0, 0, 0);
        axy1 = MFMA_BF16(xh1, ph, axy1, 0, 0, 0);
        axy1 = MFMA_BF16(xh1, pl, axy1, 0, 0, 0);
        axy1 = MFMA_BF16(xl1, ph, axy1, 0, 0, 0);
        axa0 = MFMA_BF16(xh0, ah, axa0, 0, 0, 0);
        axa0 = MFMA_BF16(xh0, al, axa0, 0, 0, 0);
        axa0 = MFMA_BF16(xl0, ah, axa0, 0, 0, 0);
        axa1 = MFMA_BF16(xh1, ah, axa1, 0, 0, 0);
        axa1 = MFMA_BF16(xh1, al, axa1, 0, 0, 0);
        axa1 = MFMA_BF16(xl1, ah, axa1, 0, 0, 0);
    }

    // -------- swap in K-half 1 of P/A --------
    __syncthreads();                       // all half-0 reads done
    if (lane >= 32) {
        #pragma unroll
        for (int i = 0; i < 8; ++i) {
            int rn = w * 8 + i;
            int cs = c0 ^ ((rn & 7) << 3);
            *(uint2*)&Phh[rn * 128 + cs] = ph1[i];
            *(uint2*)&Pll[rn * 128 + cs] = pl1[i];
            *(uint2*)&Ahh[rn * 128 + cs] = ah1[i];
            *(uint2*)&All[rn * 128 + cs] = al1[i];
        }
    }
    __syncthreads();                       // half-1 resident

    // -------- K-half 1: q = 4..7 --------
    #pragma unroll
    for (int q = 4; q < 8; ++q) {
        int kb  = (q * 32 + gb8) ^ swzA;           // X: full-K offset
        int kbB = ((q - 4) * 32 + gb8) ^ swzB;     // P/A: half tile reused
        s16x8 xh0 = *(const s16x8*)(r0h + kb);
        s16x8 xh1 = *(const s16x8*)(r1h + kb);
        s16x8 xl0 = *(const s16x8*)(r0l + kb);
        s16x8 xl1 = *(const s16x8*)(r1l + kb);
        s16x8 ph  = *(const s16x8*)(bph + kbB);
        s16x8 pl  = *(const s16x8*)(bpl + kbB);
        s16x8 ah  = *(const s16x8*)(bah + kbB);
        s16x8 al  = *(const s16x8*)(bal + kbB);
        axy0 = MFMA_BF16(xh0, ph, axy0, 0, 0, 0);
        axy0 = MFMA_BF16(xh0, pl, axy0, 0, 0, 0);
        axy0 = MFMA_BF16(xl0, ph, axy0, 0, 0, 0);
        axy1 = MFMA_BF16(xh1, ph, axy1, 0, 0, 0);
        axy1 = MFMA_BF16(xh1, pl, axy1, 0, 0, 0);
        axy1 = MFMA_BF16(xl1, ph, axy1, 0, 0, 0);
        axa0 = MFMA_BF16(xh0, ah, axa0, 0, 0, 0);
        axa0 = MFMA_BF16(xh0, al, axa0, 0, 0, 0);
        axa0 = MFMA_BF16(xl0, ah, axa0, 0, 0, 0);
        axa1 = MFMA_BF16(xh1, ah, axa1, 0, 0, 0);
        axa1 = MFMA_BF16(xh1, al, axa1, 0, 0, 0);
        axa1 = MFMA_BF16(xl1, ah, axa1, 0, 0, 0);
    }

    // -------- epilogue: C/D map col=lane&15, row=(lane>>4)*4+reg --------
    const int n = n0 + rbn;
    const float p2 = p2sl[rbn], pa = pasl[rbn], an = ansl[rbn], kk = ksl[rbn];
    #pragma unroll
    for (int m = 0; m < 2; ++m) {
        f32x4 acc_xy = m ? axy1 : axy0;
        f32x4 acc_xa = m ? axa1 : axa0;
        #pragma unroll
        for (int rg = 0; rg < 4; ++rg) {
            int bl = wr * 32 + m * 16 + (lane >> 4) * 4 + rg;
            float yy  = y2s[bl];
            float xy  = -acc_xy[rg];                     // (-P).X
            float xa  =  acc_xa[rg];
            float dnm = 1.f + 2.f * xy + p2 * yy + 1e-5f;
            float alpha = (1.f + 2.f * xy + yy) / dnm;   // coeff on (-P)
            float beta  = (1.f - p2) / dnm;              // coeff on X
            float num  = 2.f * (beta * xa - alpha * pa);
            float mob2 = alpha * alpha * p2 + beta * beta * yy
                       + 2.f * alpha * beta * xy;
            float den  = an * (1.f - mob2);
            out[(size_t)(b0 + bl) * NN + n] = kk * asinhf(num / den);
        }
    }
}

extern "C" void kernel_launch(void* const* d_in, const int* in_sizes, int n_in,
                              void* d_out, int out_size, void* d_ws, size_t ws_size,
                              hipStream_t stream) {
    const float* x      = (const float*)d_in[0];
    const float* a_vals = (const float*)d_in[1];
    const float* p_vals = (const float*)d_in[2];
    float* out = (float*)d_out;

    const int dynLds = 65536 * 2 + 5 * 64 * 4;   // tiles + scalar arrays = 132352 B
    (void)hipFuncSetAttribute(reinterpret_cast<const void*>(hmlr_fused),
                              hipFuncAttributeMaxDynamicSharedMemorySize, dynLds);

    hipLaunchKernelGGL(hmlr_fused, dim3(256), dim3(512), dynLds, stream,
                       x, a_vals, p_vals, out);
}